// Round 1
// 1531.643 us; speedup vs baseline: 1.0712x; 1.0712x over previous
//
#include <hip/hip_runtime.h>

#define NN 100000
#define NE 1600000

// broadcast lane l's value of v to all lanes (l compile-time const in unrolled loops)
__device__ __forceinline__ float rl(float v, int l) {
  return __int_as_float(__builtin_amdgcn_readlane(__float_as_int(v), l));
}

// ---------------------------------------------------------------------------
// K0: per-node prep, fully register-resident (no LDS).
//   lane j holds column j of Wq (wq[64]) and row j of Wk (wk[64]).
//   q_j = sum_i x_i * Wq[i][j]            (x broadcast via readlane)
//   g[n,h,i=lane] = sum_c Wk[lane,h*16+c] * q[h*16+c]  (q broadcast via readlane)
// Also zeroes denom[N,4] and the node-output accumulator region of d_out.
// ---------------------------------------------------------------------------
__global__ __launch_bounds__(256, 2) void node_prep(
    const float* __restrict__ x, const float* __restrict__ Wq,
    const float* __restrict__ Wk, float* __restrict__ g,
    float* __restrict__ denom, float* __restrict__ out_nodes)
{
  const int lane = threadIdx.x & 63;
  const int wid  = __builtin_amdgcn_readfirstlane(blockIdx.x * 4 + (int)(threadIdx.x >> 6));
  const int nw   = gridDim.x * 4;

  float wq[64], wk[64];
  #pragma unroll
  for (int i = 0; i < 64; i++) {
    wq[i] = Wq[i * 64 + lane];   // column `lane` of Wq
    wk[i] = Wk[lane * 64 + i];   // row    `lane` of Wk
  }

  for (int n = wid; n < NN; n += nw) {
    const float xv = x[n * 64 + lane];

    float q0 = 0.f, q1 = 0.f, q2 = 0.f, q3 = 0.f;
    #pragma unroll
    for (int i = 0; i < 64; i += 4) {
      q0 += rl(xv, i + 0) * wq[i + 0];
      q1 += rl(xv, i + 1) * wq[i + 1];
      q2 += rl(xv, i + 2) * wq[i + 2];
      q3 += rl(xv, i + 3) * wq[i + 3];
    }
    const float qv = (q0 + q1) + (q2 + q3);   // lane j holds q[n][j]

    #pragma unroll
    for (int h = 0; h < 4; h++) {
      float g0 = 0.f, g1 = 0.f, g2 = 0.f, g3 = 0.f;
      #pragma unroll
      for (int c = 0; c < 16; c += 4) {
        g0 += rl(qv, h * 16 + c + 0) * wk[h * 16 + c + 0];
        g1 += rl(qv, h * 16 + c + 1) * wk[h * 16 + c + 1];
        g2 += rl(qv, h * 16 + c + 2) * wk[h * 16 + c + 2];
        g3 += rl(qv, h * 16 + c + 3) * wk[h * 16 + c + 3];
      }
      g[n * 256 + h * 64 + lane] = (g0 + g1) + (g2 + g3);
    }

    out_nodes[n * 64 + lane] = 0.f;   // accumulator must start at 0 (0xAA poison)
    if (lane < 4) denom[n * 4 + lane] = 0.f;
  }
}

// ---------------------------------------------------------------------------
// K1: one wave per edge (grid-stride), weights register-resident
// (__launch_bounds__(256,2) so the 128-float wcol/vcol arrays do NOT spill).
// 2-deep software pipeline: edge indices (scalar loads) fetched 2 iters ahead,
// ea/x/g rows 1 iter ahead, so gather latency hides under ~500cyc of VALU.
// Reduction: xor-32/16 on all 4 heads, quarter-select, xor-8/4/2/1 on one
// value -> each 16-lane quarter ends up holding its own head's exp(score),
// which is exactly the layout the out_nodes atomic needs.
// ---------------------------------------------------------------------------
__global__ __launch_bounds__(256, 2) void edge_pass(
    const float* __restrict__ x, const int* __restrict__ ei,
    const float* __restrict__ ea, const float* __restrict__ Wv,
    const float* __restrict__ We, const float* __restrict__ be,
    const float* __restrict__ g, float* __restrict__ denom,
    float* __restrict__ out_nodes, float* __restrict__ edge_out)
{
  const int lane = threadIdx.x & 63;
  const int wid  = __builtin_amdgcn_readfirstlane(blockIdx.x * 4 + (int)(threadIdx.x >> 6));
  const int nw   = gridDim.x * 4;

  // lane j holds column j of We and Wv (128 VGPRs, intentional)
  float wcol[64], vcol[64];
  #pragma unroll
  for (int i = 0; i < 64; i++) {
    wcol[i] = We[i * 64 + lane];
    vcol[i] = Wv[i * 64 + lane];
  }
  const float bias = be[lane];

  if (wid >= NE) return;

  // ---- pipeline prologue ----
  int e1 = (wid + nw < NE) ? wid + nw : wid;       // clamped: addr valid, value unused on tail
  int s0 = ei[wid], d0 = ei[NE + wid];
  int s1 = ei[e1],  d1 = ei[NE + e1];

  float eav = ea[(size_t)wid * 64 + lane];
  float xvv = x [(size_t)d0  * 64 + lane];
  const float* gp = g + (size_t)s0 * 256;
  float g0 = gp[lane], g1 = gp[64 + lane], g2 = gp[128 + lane], g3 = gp[192 + lane];

  for (int e = wid; e < NE; e += nw) {
    // ---- prefetch: indices for e+2nw, rows for e+nw ----
    const int e2 = (e + 2 * nw < NE) ? e + 2 * nw : e;
    const int s2 = ei[e2], d2 = ei[NE + e2];

    const float ean = ea[(size_t)e1 * 64 + lane];
    const float xan = x [(size_t)d1 * 64 + lane];
    const float* gn = g + (size_t)s1 * 256;
    const float g0n = gn[lane], g1n = gn[64 + lane], g2n = gn[128 + lane], g3n = gn[192 + lane];

    // ---- compute current edge ----
    const float zv = eav * xvv;

    float p0 = zv * g0, p1 = zv * g1, p2 = zv * g2, p3 = zv * g3;
    p0 += __shfl_xor(p0, 32); p1 += __shfl_xor(p1, 32);
    p2 += __shfl_xor(p2, 32); p3 += __shfl_xor(p3, 32);
    p0 += __shfl_xor(p0, 16); p1 += __shfl_xor(p1, 16);
    p2 += __shfl_xor(p2, 16); p3 += __shfl_xor(p3, 16);
    // quarter h now needs only the 16 partials living in its own lanes
    float ph = (lane < 32) ? ((lane < 16) ? p0 : p1) : ((lane < 48) ? p2 : p3);
    ph += __shfl_xor(ph, 8);
    ph += __shfl_xor(ph, 4);
    ph += __shfl_xor(ph, 2);
    ph += __shfl_xor(ph, 1);
    const float ev = __expf(ph * 0.25f);   // quarter h holds exp(score_h)

    if ((lane & 15) == 0) atomicAdd(&denom[s0 * 4 + (lane >> 4)], ev);

    // two matvecs sharing the Z broadcast; 4 partial accs to break FMA chains
    float ae0 = bias, ae1 = 0.f, ae2 = 0.f, ae3 = 0.f;
    float av0 = 0.f,  av1 = 0.f, av2 = 0.f, av3 = 0.f;
    #pragma unroll
    for (int i = 0; i < 64; i += 4) {
      const float z0 = rl(zv, i + 0);
      const float z1 = rl(zv, i + 1);
      const float z2 = rl(zv, i + 2);
      const float z3 = rl(zv, i + 3);
      ae0 += z0 * wcol[i + 0];  av0 += z0 * vcol[i + 0];
      ae1 += z1 * wcol[i + 1];  av1 += z1 * vcol[i + 1];
      ae2 += z2 * wcol[i + 2];  av2 += z2 * vcol[i + 2];
      ae3 += z3 * wcol[i + 3];  av3 += z3 * vcol[i + 3];
    }
    edge_out[(size_t)e * 64 + lane] = (ae0 + ae1) + (ae2 + ae3);

    const float vj = (av0 + av1) + (av2 + av3);
    atomicAdd(&out_nodes[s0 * 64 + lane], ev * vj);

    // ---- rotate pipeline ----
    s0 = s1; d0 = d1; s1 = s2; d1 = d2; e1 = e2;
    eav = ean; xvv = xan;
    g0 = g0n; g1 = g1n; g2 = g2n; g3 = g3n;
  }
}

// ---------------------------------------------------------------------------
// K2: out[n, h*16+c] /= (denom[n,h] + 1e-16), float4-vectorized.
// ---------------------------------------------------------------------------
__global__ __launch_bounds__(256) void normalize_nodes(
    float4* __restrict__ out4, const float* __restrict__ denom)
{
  const int i = blockIdx.x * 256 + threadIdx.x;   // index over NN*16 float4s
  if (i < NN * 16) {
    const int n = i >> 4;          // node
    const int h = (i >> 2) & 3;    // head: col = (i&15)*4 -> head = (i&15)>>2
    const float dv = 1.0f / (denom[n * 4 + h] + 1e-16f);
    float4 v = out4[i];
    v.x *= dv; v.y *= dv; v.z *= dv; v.w *= dv;
    out4[i] = v;
  }
}

extern "C" void kernel_launch(void* const* d_in, const int* in_sizes, int n_in,
                              void* d_out, int out_size, void* d_ws, size_t ws_size,
                              hipStream_t stream) {
  const float* x  = (const float*)d_in[0];
  const int*   ei = (const int*)d_in[1];   // [2,E] int32; row0=src, row1=nbr
  const float* ea = (const float*)d_in[2];
  const float* Wq = (const float*)d_in[3];
  const float* Wk = (const float*)d_in[4];
  const float* Wv = (const float*)d_in[5];
  const float* We = (const float*)d_in[6];
  const float* be = (const float*)d_in[7];

  float* out_nodes = (float*)d_out;                 // [N,64]
  float* edge_out  = out_nodes + (size_t)NN * 64;   // [E,64]

  float* g     = (float*)d_ws;                      // [N,4,64]  = 102.4 MB
  float* denom = g + (size_t)NN * 256;              // [N,4]     = 1.6 MB

  node_prep<<<1024, 256, 0, stream>>>(x, Wq, Wk, g, denom, out_nodes);
  edge_pass<<<2048, 256, 0, stream>>>(x, ei, ea, Wv, We, be, g, denom,
                                      out_nodes, edge_out);
  normalize_nodes<<<(NN * 16 + 255) / 256, 256, 0, stream>>>(
      (float4*)out_nodes, denom);
}